// Round 1
// baseline (8134.209 us; speedup 1.0000x reference)
//
#include <hip/hip_runtime.h>
#include <hip/hip_cooperative_groups.h>
#include <cmath>

namespace cg = cooperative_groups;

// Problem constants
constexpr int B_  = 128, L_ = 128, I_ = 256, H_ = 256;
constexpr int G4_ = 1024;          // 4*H
constexpr int K_  = 512;           // I+H == H+H
constexpr int NBLK = 256;          // 64 unit-tiles x 4 batch-tiles
constexpr int NTHR = 256;
constexpr int BT = 32;             // batch rows per WG
constexpr int GR = 16;             // gate rows per WG (4 units x 4 gates)

// ws layout (float offsets)
constexpr int WSTD0 = 0;
constexpr int WSTD1 = 524288;
constexpr int BSTD0 = 1048576;
constexpr int BSTD1 = BSTD0 + 1024;
constexpr int HB0   = BSTD1 + 1024;   // 2 ping-pong buffers of 128*256
constexpr int HB1   = HB0 + 65536;
constexpr int KLP   = HB1 + 65536;    // 256 partials

// out layout (float offsets)
constexpr int HF_OFF = B_*L_*H_;           // 4194304
constexpr int CF_OFF = HF_OFF + 2*B_*H_;   // 4259840
constexpr int KL_OFF = CF_OFF + 2*B_*H_;   // 4325376

__device__ __forceinline__ float sigm(float v) { return 1.0f / (1.0f + expf(-v)); }

__global__ __launch_bounds__(NTHR, 1) void vlstm(
    const float* __restrict__ x,
    const float* __restrict__ wmu0, const float* __restrict__ wlv0,
    const float* __restrict__ bmu0, const float* __restrict__ blv0,
    const float* __restrict__ wmu1, const float* __restrict__ wlv1,
    const float* __restrict__ bmu1, const float* __restrict__ blv1,
    const float* __restrict__ epsw0, const float* __restrict__ epsb0,
    const float* __restrict__ epsw1, const float* __restrict__ epsb1,
    float* __restrict__ out, float* __restrict__ ws)
{
  cg::grid_group grid = cg::this_grid();
  const int tid = threadIdx.x;
  const int g   = blockIdx.x;
  const int bt  = g >> 6;            // 0..3
  const int ut  = g & 63;            // 0..63
  const int b0  = bt * BT;
  const int u0  = ut * 4;

  // LDS: A half-tile 32x256 (+4 pad), W half-tile 16x256 (+4 pad)
  __shared__ float As[BT][260];
  __shared__ float Wsh[GR][260];
  __shared__ float gbuf[BT][GR + 1];
  __shared__ float biass[GR];
  __shared__ float c0s[BT][4];
  __shared__ float c1s[BT][4];
  __shared__ float red[NTHR];

  float* wstd0 = ws + WSTD0;
  float* wstd1 = ws + WSTD1;
  float* bstd0 = ws + BSTD0;
  float* bstd1 = ws + BSTD1;
  float* hb0   = ws + HB0;
  float* hb1   = ws + HB1;
  float* klp   = ws + KLP;

  // ---------------- pre-phase: stds, KL partials, zero h buffers ----------------
  const int gid = g * NTHR + tid;
  const int gsz = NBLK * NTHR;   // 65536
  float kl = 0.f;
  for (int i = gid; i < 524288; i += gsz) {
    float l0 = wlv0[i], l1 = wlv1[i];
    float m0 = wmu0[i], m1 = wmu1[i];
    wstd0[i] = expf(0.5f * l0);
    wstd1[i] = expf(0.5f * l1);
    kl += 0.5f * (m0*m0 + expf(l0) - l0) + 0.5f * (m1*m1 + expf(l1) - l1);
  }
  for (int i = gid; i < G4_; i += gsz) {
    float l0 = blv0[i], l1 = blv1[i];
    float m0 = bmu0[i], m1 = bmu1[i];
    bstd0[i] = expf(0.5f * l0);
    bstd1[i] = expf(0.5f * l1);
    kl += 0.5f * (m0*m0 + expf(l0) - l0) + 0.5f * (m1*m1 + expf(l1) - l1);
  }
  for (int i = gid; i < 32768; i += gsz) {
    hb0[i] = 0.f; hb0[32768 + i] = 0.f;
    hb1[i] = 0.f; hb1[32768 + i] = 0.f;
  }
  red[tid] = kl;
  __syncthreads();
  for (int s = NTHR / 2; s > 0; s >>= 1) {
    if (tid < s) red[tid] += red[tid + s];
    __syncthreads();
  }
  if (tid == 0) klp[g] = red[0];
  if (tid < BT * 4) {
    int bl = tid >> 2, uu = tid & 3;
    c0s[bl][uu] = 0.f;
    c1s[bl][uu] = 0.f;
  }
  grid.sync();

  // compute-thread mapping: thread owns (b_l, gate rows r0,r1)
  const int jj  = tid & 7;
  const int b_l = tid >> 3;
  const int r0  = 2 * jj;
  const int r1  = r0 + 1;

  auto do_layer = [&](int layer, int t, int tau) {
    const float* wmu  = layer ? wmu1  : wmu0;
    const float* wstd = layer ? wstd1 : wstd0;
    const float* epsw = layer ? epsw1 : epsw0;
    const float* bmu  = layer ? bmu1  : bmu0;
    const float* bstd = layer ? bstd1 : bstd0;
    const float* epsb = layer ? epsb1 : epsb0;
    const float* h0prev = hb0 + ((tau - 1) & 1) * 32768;   // h0[t-? ]: see skew notes
    const float* h1prev = hb1 + (tau & 1) * 32768;         // h1[tau-2]

    float acc0 = 0.f, acc1 = 0.f;
    for (int kh = 0; kh < 2; kh++) {
      __syncthreads();   // protect LDS reuse (gbuf/A/W of previous phase fully consumed)
      // ---- stage A half-tile [32][256] ----
      #pragma unroll
      for (int p = 0; p < 8; p++) {
        int f4 = tid + p * NTHR;
        int row = f4 >> 6, c4 = f4 & 63;
        float4 v;
        if (layer == 0) {
          if (kh == 0) v = *((const float4*)(x + ((b0 + row) * L_ + t) * I_) + c4);
          else         v = *((const float4*)(h0prev + (b0 + row) * H_) + c4);
        } else {
          if (kh == 0) v = *((const float4*)(h0prev + (b0 + row) * H_) + c4);
          else         v = *((const float4*)(h1prev + (b0 + row) * H_) + c4);
        }
        *(float4*)&As[row][c4 * 4] = v;
      }
      // ---- stage W half-tile [16][256]: w = mu + eps*std ----
      #pragma unroll
      for (int p = 0; p < 4; p++) {
        int f4 = tid + p * NTHR;
        int row = f4 >> 6, c4 = f4 & 63;
        int j    = (row >> 2) * H_ + u0 + (row & 3);
        int off  = j * K_ + kh * 256 + c4 * 4;
        int eoff = (t * G4_ + j) * K_ + kh * 256 + c4 * 4;
        float4 mu = *(const float4*)(wmu + off);
        float4 sd = *(const float4*)(wstd + off);
        float4 ep = *(const float4*)(epsw + eoff);
        float4 w;
        w.x = fmaf(ep.x, sd.x, mu.x);
        w.y = fmaf(ep.y, sd.y, mu.y);
        w.z = fmaf(ep.z, sd.z, mu.z);
        w.w = fmaf(ep.w, sd.w, mu.w);
        *(float4*)&Wsh[row][c4 * 4] = w;
      }
      if (kh == 0 && tid < GR) {
        int j = (tid >> 2) * H_ + u0 + (tid & 3);
        biass[tid] = fmaf(epsb[t * G4_ + j], bstd[j], bmu[j]);
      }
      __syncthreads();
      // ---- accumulate dot products over this K-half ----
      const float4* Ar = (const float4*)&As[b_l][0];
      const float4* W0 = (const float4*)&Wsh[r0][0];
      const float4* W1 = (const float4*)&Wsh[r1][0];
      #pragma unroll 8
      for (int k4 = 0; k4 < 64; k4++) {
        float4 a = Ar[k4];
        float4 p = W0[k4];
        float4 q = W1[k4];
        acc0 = fmaf(a.x, p.x, acc0); acc0 = fmaf(a.y, p.y, acc0);
        acc0 = fmaf(a.z, p.z, acc0); acc0 = fmaf(a.w, p.w, acc0);
        acc1 = fmaf(a.x, q.x, acc1); acc1 = fmaf(a.y, q.y, acc1);
        acc1 = fmaf(a.z, q.z, acc1); acc1 = fmaf(a.w, q.w, acc1);
      }
    }
    gbuf[b_l][r0] = acc0 + biass[r0];
    gbuf[b_l][r1] = acc1 + biass[r1];
    __syncthreads();
    // ---- cell update: 128 threads, one (b,u) each ----
    if (tid < BT * 4) {
      int bl = tid >> 2, uu = tid & 3;
      float ig = gbuf[bl][0  + uu];
      float fg = gbuf[bl][4  + uu];
      float gg = gbuf[bl][8  + uu];
      float og = gbuf[bl][12 + uu];
      float si = sigm(ig), sf = sigm(fg), sg = tanhf(gg), so = sigm(og);
      float c  = layer ? c1s[bl][uu] : c0s[bl][uu];
      float cn = fmaf(sf, c, si * sg);
      float h  = so * tanhf(cn);
      int b = b0 + bl, u = u0 + uu;
      if (layer == 0) {
        c0s[bl][uu] = cn;
        hb0[(tau & 1) * 32768 + b * H_ + u] = h;
        if (t == L_ - 1) {
          out[HF_OFF + b * H_ + u] = h;
          out[CF_OFF + b * H_ + u] = cn;
        }
      } else {
        c1s[bl][uu] = cn;
        hb1[((tau - 1) & 1) * 32768 + b * H_ + u] = h;
        out[(b * L_ + t) * H_ + u] = h;
        if (t == L_ - 1) {
          out[HF_OFF + (B_ + b) * H_ + u] = h;
          out[CF_OFF + (B_ + b) * H_ + u] = cn;
        }
      }
    }
  };

  // ---------------- main skewed loop: layer0@t=tau, layer1@t=tau-1 ----------------
  for (int tau = 0; tau <= L_; tau++) {
    if (tau < L_)  do_layer(0, tau, tau);
    if (tau >= 1)  do_layer(1, tau - 1, tau);
    grid.sync();
  }

  // ---------------- final KL reduce ----------------
  if (g == 0) {
    red[tid] = klp[tid];
    __syncthreads();
    for (int s = NTHR / 2; s > 0; s >>= 1) {
      if (tid < s) red[tid] += red[tid + s];
      __syncthreads();
    }
    if (tid == 0) out[KL_OFF] = red[0];
  }
}

extern "C" void kernel_launch(void* const* d_in, const int* in_sizes, int n_in,
                              void* d_out, int out_size, void* d_ws, size_t ws_size,
                              hipStream_t stream) {
  const float* x     = (const float*)d_in[0];
  const float* wmu0  = (const float*)d_in[1];
  const float* wlv0  = (const float*)d_in[2];
  const float* bmu0  = (const float*)d_in[3];
  const float* blv0  = (const float*)d_in[4];
  const float* wmu1  = (const float*)d_in[5];
  const float* wlv1  = (const float*)d_in[6];
  const float* bmu1  = (const float*)d_in[7];
  const float* blv1  = (const float*)d_in[8];
  const float* epsw0 = (const float*)d_in[9];
  const float* epsb0 = (const float*)d_in[10];
  const float* epsw1 = (const float*)d_in[11];
  const float* epsb1 = (const float*)d_in[12];
  float* out = (float*)d_out;
  float* ws  = (float*)d_ws;

  void* args[] = {
    (void*)&x,
    (void*)&wmu0, (void*)&wlv0, (void*)&bmu0, (void*)&blv0,
    (void*)&wmu1, (void*)&wlv1, (void*)&bmu1, (void*)&blv1,
    (void*)&epsw0, (void*)&epsb0, (void*)&epsw1, (void*)&epsb1,
    (void*)&out, (void*)&ws
  };
  hipLaunchCooperativeKernel((void*)vlstm, dim3(NBLK), dim3(NTHR),
                             (void**)args, 0, stream);
}

// Round 2
// 3507.673 us; speedup vs baseline: 2.3190x; 2.3190x over previous
//
#include <hip/hip_runtime.h>
#include <hip/hip_cooperative_groups.h>
#include <cmath>

namespace cg = cooperative_groups;

// Problem constants
constexpr int B_  = 128, L_ = 128, I_ = 256, H_ = 256;
constexpr int G4_ = 1024;          // 4*H
constexpr int K_  = 512;           // I+H == H+H
constexpr int NBLK = 256;          // 64 unit-tiles x 4 batch-tiles (1 block/CU)
constexpr int NTHR = 512;          // 8 waves/CU
constexpr int BT = 32;             // batch rows per WG
constexpr int GR = 16;             // gate rows per WG (4 units x 4 gates)

// ws layout (float offsets)
constexpr int WSTD0 = 0;
constexpr int WSTD1 = 524288;
constexpr int BSTD0 = 1048576;
constexpr int BSTD1 = BSTD0 + 1024;
constexpr int HB0   = BSTD1 + 1024;   // 2 ping-pong buffers of 128*256
constexpr int HB1   = HB0 + 65536;
constexpr int KLP   = HB1 + 65536;    // 256 partials
constexpr int CNT   = KLP + 256;      // barrier counter (1 uint)

// out layout (float offsets)
constexpr int HF_OFF = B_*L_*H_;           // 4194304
constexpr int CF_OFF = HF_OFF + 2*B_*H_;   // 4259840
constexpr int KL_OFF = CF_OFF + 2*B_*H_;   // 4325376

__device__ __forceinline__ float sigm(float v) { return 1.0f / (1.0f + expf(-v)); }

// Coherent (L1/L2-bypassing) 16B load — data comes from L3, which agent-scope
// atomic stores write through to. NOTE: consumer must s_waitcnt before use;
// we batch loads into registers, then issue one waitcnt, then ds_write.
__device__ __forceinline__ float4 ld_cohere(const float* p) {
  float4 v;
  asm volatile("global_load_dwordx4 %0, %1, off sc0 sc1"
               : "=v"(v) : "v"(p) : "memory");
  return v;
}

__device__ __forceinline__ void vm_drain() {
  asm volatile("s_waitcnt vmcnt(0)" ::: "memory");
}

__global__ __launch_bounds__(NTHR, 1) void vlstm(
    const float* __restrict__ x,
    const float* __restrict__ wmu0, const float* __restrict__ wlv0,
    const float* __restrict__ bmu0, const float* __restrict__ blv0,
    const float* __restrict__ wmu1, const float* __restrict__ wlv1,
    const float* __restrict__ bmu1, const float* __restrict__ blv1,
    const float* __restrict__ epsw0, const float* __restrict__ epsb0,
    const float* __restrict__ epsw1, const float* __restrict__ epsb1,
    float* __restrict__ out, float* __restrict__ ws)
{
  cg::grid_group grid = cg::this_grid();
  const int tid = threadIdx.x;
  const int g   = blockIdx.x;
  const int bt  = g >> 6;            // 0..3
  const int ut  = g & 63;            // 0..63
  const int b0  = bt * BT;
  const int u0  = ut * 4;

  __shared__ float As[BT][260];      // generic A tile (x_t or h1prev)
  __shared__ float Hs[BT][260];      // h0prev tile, staged once per iteration
  __shared__ float Wsh[GR][260];
  __shared__ float gbuf[BT][GR + 1];
  __shared__ float biass[GR];
  __shared__ float c0s[BT][4];
  __shared__ float c1s[BT][4];
  __shared__ float red[NTHR];

  float* wstd0 = ws + WSTD0;
  float* wstd1 = ws + WSTD1;
  float* bstd0 = ws + BSTD0;
  float* bstd1 = ws + BSTD1;
  float* hb0   = ws + HB0;
  float* hb1   = ws + HB1;
  float* klp   = ws + KLP;
  unsigned* cnt = (unsigned*)(ws + CNT);

  // ---------------- pre-phase: stds, KL partials, zero h buffers ----------------
  const int gid = g * NTHR + tid;
  const int gsz = NBLK * NTHR;   // 131072
  float kl = 0.f;
  for (int i = gid; i < 524288; i += gsz) {
    float l0 = wlv0[i], l1 = wlv1[i];
    float m0 = wmu0[i], m1 = wmu1[i];
    wstd0[i] = expf(0.5f * l0);
    wstd1[i] = expf(0.5f * l1);
    kl += 0.5f * (m0*m0 + expf(l0) - l0) + 0.5f * (m1*m1 + expf(l1) - l1);
  }
  for (int i = gid; i < G4_; i += gsz) {
    float l0 = blv0[i], l1 = blv1[i];
    float m0 = bmu0[i], m1 = bmu1[i];
    bstd0[i] = expf(0.5f * l0);
    bstd1[i] = expf(0.5f * l1);
    kl += 0.5f * (m0*m0 + expf(l0) - l0) + 0.5f * (m1*m1 + expf(l1) - l1);
  }
  for (int i = gid; i < 32768; i += gsz) {
    hb0[i] = 0.f; hb0[32768 + i] = 0.f;
    hb1[i] = 0.f; hb1[32768 + i] = 0.f;
  }
  if (gid == 0) *cnt = 0u;
  red[tid] = kl;
  __syncthreads();
  for (int s = NTHR / 2; s > 0; s >>= 1) {
    if (tid < s) red[tid] += red[tid + s];
    __syncthreads();
  }
  if (tid == 0) klp[g] = red[0];
  if (tid < BT * 4) {
    int bl = tid >> 2, uu = tid & 3;
    c0s[bl][uu] = 0.f;
    c1s[bl][uu] = 0.f;
  }
  grid.sync();   // single heavy sync: publishes wstd/hb zeros/klp/cnt device-wide

  // compute mapping: thread owns (b_l, gate row r), one dot product per layer
  const int b_l = tid >> 4;          // 0..31
  const int r   = tid & 15;          // 0..15

  // W-tile staging: w = mu + eps*std, 16 rows x 256 cols (one K-half)
  auto stageW = [&](int layer, int t, int kh) {
    const float* wmu  = layer ? wmu1  : wmu0;
    const float* wstd = layer ? wstd1 : wstd0;
    const float* epsw = layer ? epsw1 : epsw0;
    #pragma unroll
    for (int p = 0; p < 2; p++) {
      int f4 = tid + p * NTHR;
      int row = f4 >> 6, c4 = f4 & 63;
      int j    = (row >> 2) * H_ + u0 + (row & 3);
      int off  = j * K_ + kh * 256 + c4 * 4;
      int eoff = (t * G4_ + j) * K_ + kh * 256 + c4 * 4;
      float4 mu = *(const float4*)(wmu + off);
      float4 sd = *(const float4*)(wstd + off);
      float4 ep = *(const float4*)(epsw + eoff);
      float4 w;
      w.x = fmaf(ep.x, sd.x, mu.x);
      w.y = fmaf(ep.y, sd.y, mu.y);
      w.z = fmaf(ep.z, sd.z, mu.z);
      w.w = fmaf(ep.w, sd.w, mu.w);
      *(float4*)&Wsh[row][c4 * 4] = w;
    }
  };
  auto stageBias = [&](int layer, int t) {
    if (tid < GR) {
      const float* bmu  = layer ? bmu1  : bmu0;
      const float* bstd = layer ? bstd1 : bstd0;
      const float* epsb = layer ? epsb1 : epsb0;
      int j = (tid >> 2) * H_ + u0 + (tid & 3);
      biass[tid] = fmaf(epsb[t * G4_ + j], bstd[j], bmu[j]);
    }
  };
  // dot of A-tile row b_l with Wsh row r over 256 cols (two chains for ILP)
  auto dot256 = [&](const float (*M)[260]) -> float {
    const float4* A4 = (const float4*)&M[b_l][0];
    const float4* W4 = (const float4*)&Wsh[r][0];
    float pa = 0.f, qa = 0.f;
    #pragma unroll 8
    for (int k = 0; k < 32; k++) {
      float4 a  = A4[k],      w  = W4[k];
      float4 a2 = A4[k + 32], w2 = W4[k + 32];
      pa = fmaf(a.x,  w.x,  pa); pa = fmaf(a.y,  w.y,  pa);
      pa = fmaf(a.z,  w.z,  pa); pa = fmaf(a.w,  w.w,  pa);
      qa = fmaf(a2.x, w2.x, qa); qa = fmaf(a2.y, w2.y, qa);
      qa = fmaf(a2.z, w2.z, qa); qa = fmaf(a2.w, w2.w, qa);
    }
    return pa + qa;
  };

  // ---------------- main skewed loop: layer0@t=tau, layer1@t=tau-1 ----------------
  for (int tau = 0; tau <= L_; tau++) {
    const int t0 = tau;
    const int t1 = tau - 1;
    const float* h0prev = hb0 + ((tau - 1) & 1) * 32768;
    const float* h1prev = hb1 + (tau & 1) * 32768;

    // ---- phase 0: stage Hs <- h0prev (coherent), As <- x_t, W(l0,kh0), bias0 ----
    __syncthreads();
    {
      float4 hv[4];
      #pragma unroll
      for (int p = 0; p < 4; p++) {
        int f4 = tid + p * NTHR;
        int row = f4 >> 6, c4 = f4 & 63;
        hv[p] = ld_cohere(h0prev + (b0 + row) * H_ + c4 * 4);
      }
      if (tau < L_) {
        #pragma unroll
        for (int p = 0; p < 4; p++) {
          int f4 = tid + p * NTHR;
          int row = f4 >> 6, c4 = f4 & 63;
          *(float4*)&As[row][c4 * 4] =
              *((const float4*)(x + ((b0 + row) * L_ + t0) * I_) + c4);
        }
        stageW(0, t0, 0);
        stageBias(0, t0);
      }
      vm_drain();   // coherent loads landed
      #pragma unroll
      for (int p = 0; p < 4; p++) {
        int f4 = tid + p * NTHR;
        int row = f4 >> 6, c4 = f4 & 63;
        *(float4*)&Hs[row][c4 * 4] = hv[p];
      }
    }
    __syncthreads();

    if (tau < L_) {
      float acc = dot256(As);            // kh0: x_t part
      __syncthreads();                   // Wsh consumed; restage
      stageW(0, t0, 1);
      __syncthreads();
      acc += dot256(Hs);                 // kh1: h0prev part
      gbuf[b_l][r] = acc + biass[r];
      __syncthreads();
      // ---- cell update layer 0 ----
      if (tid < BT * 4) {
        int bl = tid >> 2, uu = tid & 3;
        float ig = gbuf[bl][0  + uu];
        float fg = gbuf[bl][4  + uu];
        float gg = gbuf[bl][8  + uu];
        float og = gbuf[bl][12 + uu];
        float si = sigm(ig), sf = sigm(fg), sg = tanhf(gg), so = sigm(og);
        float c  = c0s[bl][uu];
        float cn = fmaf(sf, c, si * sg);
        float h  = so * tanhf(cn);
        int b = b0 + bl, u = u0 + uu;
        c0s[bl][uu] = cn;
        __hip_atomic_store(&hb0[(tau & 1) * 32768 + b * H_ + u], h,
                           __ATOMIC_RELAXED, __HIP_MEMORY_SCOPE_AGENT);
        if (t0 == L_ - 1) {
          out[HF_OFF + b * H_ + u] = h;
          out[CF_OFF + b * H_ + u] = cn;
        }
      }
    }

    if (tau >= 1) {
      // ---- layer 1 @ t1: input is h0[t1] (== Hs), recurrent is h1prev ----
      __syncthreads();                   // cell0 done reading gbuf; Wsh free
      stageW(1, t1, 0);
      stageBias(1, t1);
      __syncthreads();
      float acc = dot256(Hs);            // kh0: h0[t1] part
      __syncthreads();
      // kh1: stage As <- h1prev (coherent) + W(l1,kh1)
      {
        float4 hv[4];
        #pragma unroll
        for (int p = 0; p < 4; p++) {
          int f4 = tid + p * NTHR;
          int row = f4 >> 6, c4 = f4 & 63;
          hv[p] = ld_cohere(h1prev + (b0 + row) * H_ + c4 * 4);
        }
        stageW(1, t1, 1);
        vm_drain();
        #pragma unroll
        for (int p = 0; p < 4; p++) {
          int f4 = tid + p * NTHR;
          int row = f4 >> 6, c4 = f4 & 63;
          *(float4*)&As[row][c4 * 4] = hv[p];
        }
      }
      __syncthreads();
      acc += dot256(As);
      gbuf[b_l][r] = acc + biass[r];
      __syncthreads();
      // ---- cell update layer 1 ----
      if (tid < BT * 4) {
        int bl = tid >> 2, uu = tid & 3;
        float ig = gbuf[bl][0  + uu];
        float fg = gbuf[bl][4  + uu];
        float gg = gbuf[bl][8  + uu];
        float og = gbuf[bl][12 + uu];
        float si = sigm(ig), sf = sigm(fg), sg = tanhf(gg), so = sigm(og);
        float c  = c1s[bl][uu];
        float cn = fmaf(sf, c, si * sg);
        float h  = so * tanhf(cn);
        int b = b0 + bl, u = u0 + uu;
        c1s[bl][uu] = cn;
        __hip_atomic_store(&hb1[((tau - 1) & 1) * 32768 + b * H_ + u], h,
                           __ATOMIC_RELAXED, __HIP_MEMORY_SCOPE_AGENT);
        out[(b * L_ + t1) * H_ + u] = h;
        if (t1 == L_ - 1) {
          out[HF_OFF + (B_ + b) * H_ + u] = h;
          out[CF_OFF + (B_ + b) * H_ + u] = cn;
        }
      }
    }

    // ---- cheap grid barrier: relaxed agent atomics, no cache flushes ----
    __builtin_amdgcn_s_waitcnt(0);   // this wave's h stores are at L3
    __syncthreads();                 // all waves drained
    if (tid == 0) {
      __hip_atomic_fetch_add(cnt, 1u, __ATOMIC_RELAXED, __HIP_MEMORY_SCOPE_AGENT);
      unsigned target = (unsigned)(tau + 1) * NBLK;
      while (__hip_atomic_load(cnt, __ATOMIC_RELAXED, __HIP_MEMORY_SCOPE_AGENT) < target)
        __builtin_amdgcn_s_sleep(2);
    }
    __syncthreads();
  }

  // ---------------- final KL reduce ----------------
  if (g == 0) {
    red[tid] = (tid < NBLK) ? klp[tid] : 0.f;
    __syncthreads();
    for (int s = NTHR / 2; s > 0; s >>= 1) {
      if (tid < s) red[tid] += red[tid + s];
      __syncthreads();
    }
    if (tid == 0) out[KL_OFF] = red[0];
  }
}

extern "C" void kernel_launch(void* const* d_in, const int* in_sizes, int n_in,
                              void* d_out, int out_size, void* d_ws, size_t ws_size,
                              hipStream_t stream) {
  const float* x     = (const float*)d_in[0];
  const float* wmu0  = (const float*)d_in[1];
  const float* wlv0  = (const float*)d_in[2];
  const float* bmu0  = (const float*)d_in[3];
  const float* blv0  = (const float*)d_in[4];
  const float* wmu1  = (const float*)d_in[5];
  const float* wlv1  = (const float*)d_in[6];
  const float* bmu1  = (const float*)d_in[7];
  const float* blv1  = (const float*)d_in[8];
  const float* epsw0 = (const float*)d_in[9];
  const float* epsb0 = (const float*)d_in[10];
  const float* epsw1 = (const float*)d_in[11];
  const float* epsb1 = (const float*)d_in[12];
  float* out = (float*)d_out;
  float* ws  = (float*)d_ws;

  void* args[] = {
    (void*)&x,
    (void*)&wmu0, (void*)&wlv0, (void*)&bmu0, (void*)&blv0,
    (void*)&wmu1, (void*)&wlv1, (void*)&bmu1, (void*)&blv1,
    (void*)&epsw0, (void*)&epsb0, (void*)&epsw1, (void*)&epsb1,
    (void*)&out, (void*)&ws
  };
  hipLaunchCooperativeKernel((void*)vlstm, dim3(NBLK), dim3(NTHR),
                             (void**)args, 0, stream);
}